// Round 13
// baseline (1120.767 us; speedup 1.0000x reference)
//
#include <hip/hip_runtime.h>
#include <hip/hip_bf16.h>

#define BB 8
#define NN 2048
#define KK 20
#define BBNN (BB * NN)

typedef __hip_bfloat16 bf16;
typedef unsigned short u16;
typedef __attribute__((ext_vector_type(8))) short short8;
typedef __attribute__((ext_vector_type(4))) float f32x4;

__device__ __forceinline__ float b2f(bf16 v) { return __bfloat162float(v); }

// ---------------------------------------------------------------- sq + transpose (fused)
template<int C>
__global__ __launch_bounds__(256) void sqT_kernel(const float* __restrict__ xin,
                                                  float* __restrict__ sq,
                                                  float* __restrict__ xT) {
    int t = blockIdx.x * 256 + threadIdx.x;
    if (t >= BBNN) return;
    const float* p = xin + (size_t)t * C;
    float s = 0.f;
    for (int c = 0; c < C; ++c) {
        float v = p[c];
        s += v * v;
        xT[(size_t)c * BBNN + t] = v;
    }
    sq[t] = s;
}

// ---------------------------------------------------------------- fast kNN v4.1
// Identical structure to v4 (2 queries/wave, ds_read_b128 phase A, register
// phase B) but __launch_bounds__(512, 2): VGPR ceiling 256 so the ~100-reg
// working set (dA[32]+dB[32]+xq+misc) is NOT spilled to scratch (round-12
// counters: VGPR_Count=64 + 51 MB scratch writes at (512,4)). Actual alloc
// ~110 -> HW still fits ~4 waves/EU.
template<int C, int CH>
__global__ __launch_bounds__(512, 2) void knn_fast_kernel(
        const float* __restrict__ xrows,   // [BBNN][C] row-major (query reads)
        const float* __restrict__ xT,      // [C][BBNN] transposed (neighbor reads)
        const float* __restrict__ sq,
        u16* __restrict__ idx_out) {
    __shared__ __align__(16) float xs[CH][256];
    const int blk = blockIdx.x;            // BB * 128
    const int b = blk >> 7;
    const int tile = blk & 127;
    const int w = threadIdx.x >> 6;
    const int s = threadIdx.x & 63;
    const int iA = tile * 16 + w * 2;
    const int bn0 = b * NN;
    constexpr int NCH = C / CH;

    float dA[32], dB[32];
    #pragma unroll
    for (int r = 0; r < 32; ++r) { dA[r] = 0.f; dB[r] = 0.f; }

    const int qbaseA = __builtin_amdgcn_readfirstlane((bn0 + iA) * C);
    for (int ch = 0; ch < NCH; ++ch) {
        float xqA[CH], xqB[CH];
        #pragma unroll
        for (int cc = 0; cc < CH; ++cc) {
            xqA[cc] = xrows[qbaseA + ch * CH + cc];
            xqB[cc] = xrows[qbaseA + C + ch * CH + cc];
        }
        #pragma unroll 1
        for (int t = 0; t < 8; ++t) {
            __syncthreads();
            for (int p = threadIdx.x; p < CH * 64; p += 512) {
                int c = p >> 6, j4 = (p & 63) << 2;
                *(float4*)&xs[c][j4] =
                    *(const float4*)(xT + (size_t)(ch * CH + c) * BBNN + bn0 + t * 256 + j4);
            }
            __syncthreads();
            float aA0 = 0.f, aA1 = 0.f, aA2 = 0.f, aA3 = 0.f;
            float aB0 = 0.f, aB1 = 0.f, aB2 = 0.f, aB3 = 0.f;
            #pragma unroll
            for (int cc = 0; cc < CH; ++cc) {
                float4 xv = *(const float4*)&xs[cc][s * 4];
                float qA = xqA[cc], qB = xqB[cc];
                aA0 += qA * xv.x; aA1 += qA * xv.y; aA2 += qA * xv.z; aA3 += qA * xv.w;
                aB0 += qB * xv.x; aB1 += qB * xv.y; aB2 += qB * xv.z; aB3 += qB * xv.w;
            }
            dA[t * 4 + 0] += aA0; dA[t * 4 + 1] += aA1;
            dA[t * 4 + 2] += aA2; dA[t * 4 + 3] += aA3;
            dB[t * 4 + 0] += aB0; dB[t * 4 + 1] += aB1;
            dB[t * 4 + 2] += aB2; dB[t * 4 + 3] += aB3;
        }
    }
    const float sqiA = sq[bn0 + iA];
    const float sqiB = sq[bn0 + iA + 1];
    #pragma unroll
    for (int r = 0; r < 32; ++r) {
        int j = ((r >> 2) << 8) + (s << 2) + (r & 3);
        float sqj = sq[bn0 + j];
        dA[r] = (sqiA + sqj) - 2.f * dA[r];
        dB[r] = (sqiB + sqj) - 2.f * dB[r];
    }

    {
        float ld = INFINITY; int lj = 0x7fffffff;
        #pragma unroll
        for (int r = 0; r < 32; ++r) {
            int j = ((r >> 2) << 8) + (s << 2) + (r & 3);
            if (dA[r] < ld) { ld = dA[r]; lj = j; }
        }
        for (int k = 0; k < KK; ++k) {
            float rd = ld; int rj = lj;
            #pragma unroll
            for (int m = 1; m < 64; m <<= 1) {
                float od = __shfl_xor(rd, m);
                int   oj = __shfl_xor(rj, m);
                if (od < rd || (od == rd && oj < rj)) { rd = od; rj = oj; }
            }
            if (s == 0) idx_out[(size_t)(bn0 + iA) * KK + k] = (u16)rj;
            if (k + 1 < KK) {
                if (s == ((rj & 255) >> 2)) {
                    int rr = ((rj >> 8) << 2) + (rj & 3);
                    ld = INFINITY; lj = 0x7fffffff;
                    #pragma unroll
                    for (int r = 0; r < 32; ++r) {
                        if (r == rr) dA[r] = INFINITY;
                        int j = ((r >> 2) << 8) + (s << 2) + (r & 3);
                        if (dA[r] < ld) { ld = dA[r]; lj = j; }
                    }
                }
            }
        }
    }
    {
        float ld = INFINITY; int lj = 0x7fffffff;
        #pragma unroll
        for (int r = 0; r < 32; ++r) {
            int j = ((r >> 2) << 8) + (s << 2) + (r & 3);
            if (dB[r] < ld) { ld = dB[r]; lj = j; }
        }
        for (int k = 0; k < KK; ++k) {
            float rd = ld; int rj = lj;
            #pragma unroll
            for (int m = 1; m < 64; m <<= 1) {
                float od = __shfl_xor(rd, m);
                int   oj = __shfl_xor(rj, m);
                if (od < rd || (od == rd && oj < rj)) { rd = od; rj = oj; }
            }
            if (s == 0) idx_out[(size_t)(bn0 + iA + 1) * KK + k] = (u16)rj;
            if (k + 1 < KK) {
                if (s == ((rj & 255) >> 2)) {
                    int rr = ((rj >> 8) << 2) + (rj & 3);
                    ld = INFINITY; lj = 0x7fffffff;
                    #pragma unroll
                    for (int r = 0; r < 32; ++r) {
                        if (r == rr) dB[r] = INFINITY;
                        int j = ((r >> 2) << 8) + (s << 2) + (r & 3);
                        if (dB[r] < ld) { ld = dB[r]; lj = j; }
                    }
                }
            }
        }
    }
}

// ---------------------------------------------------------------- G[n][h] = x[n] . w1_lower[.][h]
template<int CIN>
__global__ __launch_bounds__(256) void gemmG_kernel(const float* __restrict__ xin,
                                                    const float* __restrict__ w1,
                                                    float* __restrict__ G) {
    __shared__ float wls[CIN * 64];
    __shared__ float xr[4][CIN];
    const int bn0 = blockIdx.x * 4;
    const int tid = threadIdx.x;
    for (int p = tid; p < CIN * 64; p += 256) wls[p] = w1[CIN * 64 + p];
    for (int p = tid; p < 4 * CIN; p += 256)
        xr[p / CIN][p % CIN] = xin[(size_t)bn0 * CIN + p];
    __syncthreads();
    const int pp = tid >> 6, h = tid & 63;
    float a = 0.f;
    for (int c = 0; c < CIN; ++c) a += xr[pp][c] * wls[c * 64 + h];
    G[(size_t)(bn0 + pp) * 64 + h] = a;
}

// ---------------------------------------------------------------- EdgeConv v3: G-decomposed
template<int CIN, int COUT, bool BF16OUT>
__global__ __launch_bounds__(256) void edgeconv3_kernel(
        const float* __restrict__ xin, const u16* __restrict__ knn,
        const float* __restrict__ w1, const float* __restrict__ b1,
        const float* __restrict__ w2, const float* __restrict__ b2,
        const float* __restrict__ G, void* __restrict__ out) {
    constexpr int SPLIT = 256 / COUT;
    constexpr int KPS = KK / SPLIT;
    const int bn0 = blockIdx.x * 4;
    const int b = bn0 >> 11;
    const int tid = threadIdx.x;
    __shared__ float w1us[CIN * 64];
    __shared__ float xr[4][CIN];
    __shared__ __align__(16) float h1s[4][KK][64];
    __shared__ float pms[4][SPLIT][COUT];
    __shared__ int js[4][KK];

    for (int p = tid; p < CIN * 64; p += 256) w1us[p] = w1[p];
    for (int p = tid; p < 4 * CIN; p += 256)
        xr[p / CIN][p % CIN] = xin[(size_t)bn0 * CIN + p];
    if (tid < 4 * KK) {
        int j = knn[(size_t)(bn0 + tid / KK) * KK + (tid % KK)];
        js[tid / KK][tid % KK] = (j < NN) ? j : 0;
    }
    __syncthreads();

    {
        const int pp = tid >> 6, h = tid & 63;
        float u = b1[h];
        for (int c = 0; c < CIN; ++c) u += xr[pp][c] * w1us[c * 64 + h];
        u -= G[(size_t)(bn0 + pp) * 64 + h];
        const float* Gb = G + (size_t)b * NN * 64 + h;
        for (int k = 0; k < KK; ++k) {
            float gj = Gb[(size_t)js[pp][k] * 64];
            h1s[pp][k][h] = fmaxf(u + gj, 0.f);
        }
    }
    __syncthreads();

    {
        const int o = tid % COUT, ks = tid / COUT;
        float wcol[64];
        #pragma unroll
        for (int c = 0; c < 64; ++c) wcol[c] = w2[c * COUT + o];
        #pragma unroll
        for (int pp = 0; pp < 4; ++pp) {
            float mx = -INFINITY;
            for (int k = ks * KPS; k < (ks + 1) * KPS; ++k) {
                float acc = 0.f;
                #pragma unroll
                for (int c4 = 0; c4 < 16; ++c4) {
                    float4 hv = *(const float4*)&h1s[pp][k][c4 * 4];
                    acc += hv.x * wcol[c4 * 4 + 0];
                    acc += hv.y * wcol[c4 * 4 + 1];
                    acc += hv.z * wcol[c4 * 4 + 2];
                    acc += hv.w * wcol[c4 * 4 + 3];
                }
                mx = fmaxf(mx, acc);
            }
            pms[pp][ks][o] = mx;
        }
    }
    __syncthreads();
    for (int idx = tid; idx < 4 * COUT; idx += 256) {
        int pp = idx / COUT, oo = idx % COUT;
        float mx = pms[pp][0][oo];
        #pragma unroll
        for (int s2 = 1; s2 < SPLIT; ++s2) mx = fmaxf(mx, pms[pp][s2][oo]);
        mx += b2[oo];
        if (BF16OUT) ((bf16*)out)[(size_t)(bn0 + pp) * COUT + oo] = __float2bfloat16(mx);
        else         ((float*)out)[(size_t)(bn0 + pp) * COUT + oo] = mx;
    }
}

// ---------------------------------------------------------------- global max over N (2-stage)
__global__ __launch_bounds__(128) void gmax1_kernel(const bf16* __restrict__ f2,
                                                    float* __restrict__ pmax) {
    const int b = blockIdx.x >> 4, ch = blockIdx.x & 15, c = threadIdx.x;
    float m = -INFINITY;
    const bf16* base = f2 + ((size_t)(b * NN + ch * 128)) * 128 + c;
    for (int n = 0; n < 128; ++n) m = fmaxf(m, b2f(base[(size_t)n * 128]));
    pmax[blockIdx.x * 128 + c] = m;
}

__global__ __launch_bounds__(128) void gmax2_kernel(const float* __restrict__ pmax,
                                                    float* __restrict__ glob) {
    const int b = blockIdx.x, c = threadIdx.x;
    float m = -INFINITY;
    for (int ch = 0; ch < 16; ++ch) m = fmaxf(m, pmax[(b * 16 + ch) * 128 + c]);
    glob[b * 128 + c] = m;
}

// ---------------------------------------------------------------- K + V^T for all heads
__global__ __launch_bounds__(256) void kvt_kernel(const bf16* __restrict__ f2,
                                                  const float* __restrict__ qkv_w,
                                                  bf16* __restrict__ kk,
                                                  bf16* __restrict__ vt) {
    const int blk = blockIdx.x;
    const int h = blk >> 12;
    const int rg = blk & 4095;
    const int bn0 = rg * 4;
    const int b = bn0 >> 11, n0 = bn0 & 2047;
    const int tid = threadIdx.x;
    __shared__ float Ws[2][128][32];
    __shared__ float f2s[4][128];
    __shared__ float vbuf[4][32];
    for (int p = tid; p < 2 * 128 * 32; p += 256) {
        int kv = p >> 12, c = (p >> 5) & 127, d = p & 31;
        Ws[kv][c][d] = qkv_w[c * 384 + 128 + kv * 128 + h * 32 + d];
    }
    for (int p = tid; p < 4 * 128; p += 256) {
        int rr = p >> 7, c = p & 127;
        f2s[rr][c] = b2f(f2[(size_t)(bn0 + rr) * 128 + c]);
    }
    __syncthreads();
    const int rr = tid >> 6, u = tid & 63, kv = u >> 5, d = u & 31;
    float acc = 0.f;
    for (int c = 0; c < 128; ++c) acc += f2s[rr][c] * Ws[kv][c][d];
    if (kv == 0)
        kk[((size_t)(b * 4 + h) * 2048 + n0 + rr) * 32 + d] = __float2bfloat16(acc);
    else
        vbuf[rr][d] = acc;
    __syncthreads();
    if (tid < 128) {
        int dd = tid >> 2, r2 = tid & 3;
        vt[((size_t)(b * 4 + h) * 32 + dd) * 2048 + n0 + r2] = __float2bfloat16(vbuf[r2][dd]);
    }
}

// ---------------------------------------------------------------- MFMA flash attention
__global__ __launch_bounds__(256) void attn_mfma_kernel(
        const bf16* __restrict__ f2, const float* __restrict__ qkv_w,
        const bf16* __restrict__ kk, const bf16* __restrict__ vt,
        bf16* __restrict__ atth) {
    const int blk = blockIdx.x;
    const int tile = blk & 31;
    const int h = (blk >> 5) & 3;
    const int b = blk >> 7;
    const int tid = threadIdx.x;
    const int w = tid >> 6;
    const int lane = tid & 63;
    const int lq = lane & 15;
    const int quad = lane >> 4;
    const float scale = 0.17677669529663687f;

    __shared__ __align__(16) bf16 WqT[32][128];
    __shared__ __align__(16) bf16 pbuf[4][2][16][32];

    for (int p = tid; p < 4096; p += 256) {
        int c = p >> 5, d = p & 31;
        WqT[d][c] = __float2bfloat16(qkv_w[c * 384 + h * 32 + d]);
    }
    __syncthreads();

    const int q0 = tile * 64 + w * 16;
    const bf16* fbase = f2 + ((size_t)(b * NN + q0 + lq)) * 128;
    f32x4 qc0 = {0.f, 0.f, 0.f, 0.f}, qc1 = {0.f, 0.f, 0.f, 0.f};
    #pragma unroll
    for (int kc = 0; kc < 4; ++kc) {
        short8 af = *(const short8*)(fbase + kc * 32 + quad * 8);
        short8 b0 = *(const short8*)(&WqT[lq][kc * 32 + quad * 8]);
        short8 b1 = *(const short8*)(&WqT[16 + lq][kc * 32 + quad * 8]);
        qc0 = __builtin_amdgcn_mfma_f32_16x16x32_bf16(af, b0, qc0, 0, 0, 0);
        qc1 = __builtin_amdgcn_mfma_f32_16x16x32_bf16(af, b1, qc1, 0, 0, 0);
    }
    {
        bf16* pw = &pbuf[w][0][0][0];
        #pragma unroll
        for (int r = 0; r < 4; ++r) {
            int qq = quad * 4 + r;
            pw[qq * 32 + lq]      = __float2bfloat16(qc0[r] * scale);
            pw[qq * 32 + 16 + lq] = __float2bfloat16(qc1[r] * scale);
        }
    }
    __syncthreads();
    const short8 qfrag = *(const short8*)(&pbuf[w][0][lq][quad * 8]);
    __syncthreads();

    const bf16* kb = kk + (size_t)(b * 4 + h) * 2048 * 32;
    const bf16* vb = vt + (size_t)(b * 4 + h) * 32 * 2048;
    f32x4 o0 = {0.f, 0.f, 0.f, 0.f}, o1 = {0.f, 0.f, 0.f, 0.f};
    f32x4 lsum = {0.f, 0.f, 0.f, 0.f};
    const short8 ones = {(short)0x3F80, (short)0x3F80, (short)0x3F80, (short)0x3F80,
                         (short)0x3F80, (short)0x3F80, (short)0x3F80, (short)0x3F80};

    for (int ch = 0; ch < 64; ++ch) {
        const int j0 = ch * 32;
        short8 kf0 = *(const short8*)(kb + (size_t)(j0 + lq) * 32 + quad * 8);
        short8 kf1 = *(const short8*)(kb + (size_t)(j0 + 16 + lq) * 32 + quad * 8);
        f32x4 z = {0.f, 0.f, 0.f, 0.f};
        f32x4 s0 = __builtin_amdgcn_mfma_f32_16x16x32_bf16(qfrag, kf0, z, 0, 0, 0);
        f32x4 s1 = __builtin_amdgcn_mfma_f32_16x16x32_bf16(qfrag, kf1, z, 0, 0, 0);
        bf16* pw = &pbuf[w][ch & 1][0][0];
        #pragma unroll
        for (int r = 0; r < 4; ++r) {
            int qq = quad * 4 + r;
            pw[qq * 32 + lq]      = __float2bfloat16(__expf(s0[r]));
            pw[qq * 32 + 16 + lq] = __float2bfloat16(__expf(s1[r]));
        }
        __syncthreads();
        short8 pf = *(const short8*)(pw + lq * 32 + quad * 8);
        short8 vf0 = *(const short8*)(vb + (size_t)lq * 2048 + j0 + quad * 8);
        short8 vf1 = *(const short8*)(vb + (size_t)(16 + lq) * 2048 + j0 + quad * 8);
        o0   = __builtin_amdgcn_mfma_f32_16x16x32_bf16(pf, vf0, o0, 0, 0, 0);
        o1   = __builtin_amdgcn_mfma_f32_16x16x32_bf16(pf, vf1, o1, 0, 0, 0);
        lsum = __builtin_amdgcn_mfma_f32_16x16x32_bf16(pf, ones, lsum, 0, 0, 0);
    }

    #pragma unroll
    for (int r = 0; r < 4; ++r) {
        int row = q0 + quad * 4 + r;
        float inv = 1.f / lsum[r];
        bf16* orow = atth + ((size_t)(b * NN + row)) * 128 + h * 32;
        orow[lq]      = __float2bfloat16(o0[r] * inv);
        orow[16 + lq] = __float2bfloat16(o1[r] * inv);
    }
}

// ---------------------------------------------------------------- fused out-proj + concat + refine MLP + log_softmax
__global__ __launch_bounds__(128) void final_kernel(
        const bf16* __restrict__ f2, const float* __restrict__ glob,
        const bf16* __restrict__ atth,
        const float* __restrict__ out_w, const float* __restrict__ out_b,
        const float* __restrict__ r1_w, const float* __restrict__ r1_b,
        const float* __restrict__ r2_w, const float* __restrict__ r2_b,
        const float* __restrict__ r3_w, const float* __restrict__ r3_b,
        float* __restrict__ out) {
    const int bn0 = blockIdx.x * 4;
    const int b = bn0 >> 11;
    const int tid = threadIdx.x;
    __shared__ float attin[4][128], comb[4][384], h1[4][128], h2[4][64];
    __shared__ float logits[4][20], lse[4];

    #pragma unroll
    for (int rr = 0; rr < 4; ++rr) {
        attin[rr][tid]      = b2f(atth[(size_t)(bn0 + rr) * 128 + tid]);
        comb[rr][tid]       = b2f(f2[(size_t)(bn0 + rr) * 128 + tid]);
        comb[rr][128 + tid] = glob[b * 128 + tid];
    }
    __syncthreads();
    {
        float a0 = 0.f, a1 = 0.f, a2 = 0.f, a3 = 0.f;
        for (int c = 0; c < 128; ++c) {
            float wv = out_w[c * 128 + tid];
            a0 += attin[0][c] * wv; a1 += attin[1][c] * wv;
            a2 += attin[2][c] * wv; a3 += attin[3][c] * wv;
        }
        float bb = out_b[tid];
        comb[0][256 + tid] = a0 + bb; comb[1][256 + tid] = a1 + bb;
        comb[2][256 + tid] = a2 + bb; comb[3][256 + tid] = a3 + bb;
    }
    __syncthreads();
    {
        float a0 = 0.f, a1 = 0.f, a2 = 0.f, a3 = 0.f;
        for (int c = 0; c < 384; ++c) {
            float wv = r1_w[c * 128 + tid];
            a0 += comb[0][c] * wv; a1 += comb[1][c] * wv;
            a2 += comb[2][c] * wv; a3 += comb[3][c] * wv;
        }
        float bb = r1_b[tid];
        h1[0][tid] = fmaxf(a0 + bb, 0.f); h1[1][tid] = fmaxf(a1 + bb, 0.f);
        h1[2][tid] = fmaxf(a2 + bb, 0.f); h1[3][tid] = fmaxf(a3 + bb, 0.f);
    }
    __syncthreads();
    if (tid < 64) {
        float a0 = 0.f, a1 = 0.f, a2 = 0.f, a3 = 0.f;
        for (int c = 0; c < 128; ++c) {
            float wv = r2_w[c * 64 + tid];
            a0 += h1[0][c] * wv; a1 += h1[1][c] * wv;
            a2 += h1[2][c] * wv; a3 += h1[3][c] * wv;
        }
        float bb = r2_b[tid];
        h2[0][tid] = fmaxf(a0 + bb, 0.f); h2[1][tid] = fmaxf(a1 + bb, 0.f);
        h2[2][tid] = fmaxf(a2 + bb, 0.f); h2[3][tid] = fmaxf(a3 + bb, 0.f);
    }
    __syncthreads();
    if (tid < 20) {
        float a0 = 0.f, a1 = 0.f, a2 = 0.f, a3 = 0.f;
        for (int c = 0; c < 64; ++c) {
            float wv = r3_w[c * 20 + tid];
            a0 += h2[0][c] * wv; a1 += h2[1][c] * wv;
            a2 += h2[2][c] * wv; a3 += h2[3][c] * wv;
        }
        float bb = r3_b[tid];
        logits[0][tid] = a0 + bb; logits[1][tid] = a1 + bb;
        logits[2][tid] = a2 + bb; logits[3][tid] = a3 + bb;
    }
    __syncthreads();
    if (tid < 4) {
        float m = -INFINITY;
        for (int u = 0; u < 20; ++u) m = fmaxf(m, logits[tid][u]);
        float s = 0.f;
        for (int u = 0; u < 20; ++u) s += expf(logits[tid][u] - m);
        lse[tid] = m + logf(s);
    }
    __syncthreads();
    if (tid < 80) {
        int rr = tid / 20, cls = tid % 20;
        out[(size_t)(bn0 + rr) * 20 + cls] = logits[rr][cls] - lse[rr];
    }
}

// ----------------------------------------------------------------------------
// Layout (ws >= NEED_A = 16,846,848 B — proven):
//   [0,4M)       f1T (phases 1-3) -> f2 bf16 (phase 3+)
//   [4M,+64K)    sqb | [4M+64K,8M+64K) f1 | [8M+64K,+640K) knn | +192K xT3
//   [4M,8M)      kkA (after ec2) | [8M,12M) vtA
//   [12M,16M)    G (phases 1-3) -> atth (attention phase)
//   [16M,+68K)   pmax | glob
extern "C" void kernel_launch(void* const* d_in, const int* in_sizes, int n_in,
                              void* d_out, int out_size, void* d_ws, size_t ws_size,
                              hipStream_t stream) {
    const float* x      = (const float*)d_in[0];
    const float* ec1_w1 = (const float*)d_in[2];
    const float* ec1_b1 = (const float*)d_in[3];
    const float* ec1_w2 = (const float*)d_in[4];
    const float* ec1_b2 = (const float*)d_in[5];
    const float* ec2_w1 = (const float*)d_in[6];
    const float* ec2_b1 = (const float*)d_in[7];
    const float* ec2_w2 = (const float*)d_in[8];
    const float* ec2_b2 = (const float*)d_in[9];
    const float* qkv_w  = (const float*)d_in[10];
    const float* out_w  = (const float*)d_in[11];
    const float* out_b  = (const float*)d_in[12];
    const float* r1_w   = (const float*)d_in[13];
    const float* r1_b   = (const float*)d_in[14];
    const float* r2_w   = (const float*)d_in[15];
    const float* r2_b   = (const float*)d_in[16];
    const float* r3_w   = (const float*)d_in[17];
    const float* r3_b   = (const float*)d_in[18];
    float* out = (float*)d_out;

    const size_t MB = 1024 * 1024;
    const size_t NEED_A = 16 * MB + 65536 + 4096;
    if (ws_size < NEED_A) return;

    char* base = (char*)d_ws;
    bf16*  f2   = (bf16*)(base);
    float* f1T  = (float*)(base);
    float* sqb  = (float*)(base + 4 * MB);
    float* f1   = (float*)(base + 4 * MB + 65536);
    u16*   knn  = (u16*)(base + 8 * MB + 65536);
    float* xT3  = (float*)(base + 8 * MB + 65536 + 655360);
    float* G    = (float*)(base + 12 * MB);
    bf16*  kkA  = (bf16*)(base + 4 * MB);
    bf16*  vtA  = (bf16*)(base + 8 * MB);
    bf16*  atth = (bf16*)(base + 12 * MB);
    float* pmax = (float*)(base + 16 * MB);
    float* glob = (float*)(base + 16 * MB + 65536);

    sqT_kernel<3><<<BBNN / 256, 256, 0, stream>>>(x, sqb, xT3);
    knn_fast_kernel<3, 3><<<BB * 128, 512, 0, stream>>>(x, xT3, sqb, knn);
    gemmG_kernel<3><<<BBNN / 4, 256, 0, stream>>>(x, ec1_w1, G);
    edgeconv3_kernel<3, 64, false><<<BBNN / 4, 256, 0, stream>>>(
        x, knn, ec1_w1, ec1_b1, ec1_w2, ec1_b2, G, f1);

    sqT_kernel<64><<<BBNN / 256, 256, 0, stream>>>(f1, sqb, f1T);
    knn_fast_kernel<64, 8><<<BB * 128, 512, 0, stream>>>(f1, f1T, sqb, knn);
    gemmG_kernel<64><<<BBNN / 4, 256, 0, stream>>>(f1, ec2_w1, G);
    edgeconv3_kernel<64, 128, true><<<BBNN / 4, 256, 0, stream>>>(
        f1, knn, ec2_w1, ec2_b1, ec2_w2, ec2_b2, G, f2);

    gmax1_kernel<<<BB * 16, 128, 0, stream>>>(f2, pmax);
    gmax2_kernel<<<BB, 128, 0, stream>>>(pmax, glob);

    kvt_kernel<<<4 * BBNN / 4, 256, 0, stream>>>(f2, qkv_w, kkA, vtA);
    attn_mfma_kernel<<<BB * 4 * 32, 256, 0, stream>>>(f2, qkv_w, kkA, vtA, atth);

    final_kernel<<<BBNN / 4, 128, 0, stream>>>(
        f2, glob, atth, out_w, out_b, r1_w, r1_b, r2_w, r2_b, r3_w, r3_b, out);
}